// Round 3
// baseline (564.187 us; speedup 1.0000x reference)
//
#include <hip/hip_runtime.h>
#include <hip/hip_bf16.h>

// SpatialTransformer bilinear warp, N=4 C=32 H=512 W=512, fp32.
// Round 3: fused LDS-tiled single kernel (no transpose pass).
//   block = one 64x32 pixel tile of one batch n (512 blocks, 512 threads).
//   Stage src region (96x64 = tile + +/-16 halo) per channel into LDS
//   (double-buffered, 51.2 KB), coalesced straight from NCHW.
//   Per-pixel weights/taps computed once; 32-channel loop gathers 4 LDS
//   taps, FMAs, stores coalesced NCHW. Rare |flow|>16 outliers take a
//   predicated per-pixel global-gather fallback (exactness preserved).

constexpr int N_ = 4, C_ = 32, H_ = 512, W_ = 512;
constexpr size_t PLANE = (size_t)H_ * W_;

constexpr int TW = 64, TH = 32;          // tile (pixels)
constexpr int PAD = 16;                  // halo
constexpr int RW = TW + 2 * PAD;         // 96 region cols
constexpr int RH = TH + 2 * PAD;         // 64 region rows
constexpr int LSTR = 100;                // LDS row stride (floats): 400 B, 16B-aligned
constexpr int NTHREADS = 512;
constexpr int PXT = TW * TH / NTHREADS;  // 4 pixels per thread
constexpr int NF4 = (RW / 4) * RH;       // 1536 float4 per channel stage
constexpr int LD4 = NF4 / NTHREADS;      // 3 float4 stage loads per thread

__global__ __launch_bounds__(NTHREADS, 6) void st_warp_tiled(
    const float* __restrict__ src, const float* __restrict__ flow,
    float* __restrict__ out) {
    __shared__ float lds[2][RH * LSTR];  // 2 x 25.6 KB

    const int tid = threadIdx.x;
    const int b = blockIdx.x;            // n(2b) | ty(4b) | tx(3b)
    const int tx = b & 7;
    const int ty = (b >> 3) & 15;
    const int n = b >> 7;

    const int x0 = tx * TW, y0 = ty * TH;
    const int xs = x0 - PAD, ys = y0 - PAD;

    // ---------- Phase A: per-pixel geometry (once) ----------
    float wt[PXT][4];
    int op2[PXT][2];   // packed LDS byte offsets: [0]=(oB<<16)|oA, [1]=(oD<<16)|oC
    int pc[PXT][2];    // packed clamped coords (y<<16)|x: [0]=A(yac,xac), [1]=D(ybc,xbc)
    unsigned okmask = 0;

    #pragma unroll
    for (int k = 0; k < PXT; ++k) {
        int p = tid + k * NTHREADS;
        int lx = p & (TW - 1);
        int ly = p >> 6;
        int px = x0 + lx, py = y0 + ly;

        const float* f = flow + (size_t)n * 2 * PLANE + (size_t)py * W_ + px;
        float fx = f[0];
        float fy = f[PLANE];

        // replicate reference math exactly
        float xl = (float)px + fx;
        float yl = (float)py + fy;
        float xn = 2.0f * (xl / (float)(W_ - 1) - 0.5f);
        float yn = 2.0f * (yl / (float)(H_ - 1) - 0.5f);
        float x = (xn + 1.0f) / 2.0f * (float)(W_ - 1);
        float y = (yn + 1.0f) / 2.0f * (float)(H_ - 1);

        float x0f = floorf(x), y0f = floorf(y);
        float x1f = x0f + 1.0f, y1f = y0f + 1.0f;
        int ix0 = (int)x0f, iy0 = (int)y0f;

        int xa = min(max(ix0 + 1, 0), W_ + 1) - 1;   // [-1, W]
        int xb = min(max(ix0 + 2, 0), W_ + 1) - 1;
        int ya = min(max(iy0 + 1, 0), H_ + 1) - 1;
        int yb = min(max(iy0 + 2, 0), H_ + 1) - 1;

        float vxa = ((unsigned)xa < (unsigned)W_) ? 1.0f : 0.0f;
        float vxb = ((unsigned)xb < (unsigned)W_) ? 1.0f : 0.0f;
        float vya = ((unsigned)ya < (unsigned)H_) ? 1.0f : 0.0f;
        float vyb = ((unsigned)yb < (unsigned)H_) ? 1.0f : 0.0f;

        float axw = (x1f - x) * vxa;
        float bxw = (x - x0f) * vxb;
        float ayw = (y1f - y) * vya;
        float byw = (y - y0f) * vyb;

        wt[k][0] = axw * ayw;   // A (x0,y0)
        wt[k][1] = axw * byw;   // B (x0,y1)
        wt[k][2] = bxw * ayw;   // C (x1,y0)
        wt[k][3] = bxw * byw;   // D (x1,y1)

        int xac = min(max(xa, 0), W_ - 1);
        int xbc = min(max(xb, 0), W_ - 1);
        int yac = min(max(ya, 0), H_ - 1);
        int ybc = min(max(yb, 0), H_ - 1);

        bool ok = (xac >= xs) && (xbc < xs + RW) && (yac >= ys) && (ybc < ys + RH);
        okmask |= (ok ? 1u : 0u) << k;

        // LDS byte offsets (valid only when ok; max 25568, fits 16 bits)
        int oA = ((yac - ys) * LSTR + (xac - xs)) * 4;
        int oB = ((ybc - ys) * LSTR + (xac - xs)) * 4;
        int oC = ((yac - ys) * LSTR + (xbc - xs)) * 4;
        int oD = ((ybc - ys) * LSTR + (xbc - xs)) * 4;
        op2[k][0] = (oB << 16) | (oA & 0xffff);
        op2[k][1] = (oD << 16) | (oC & 0xffff);
        pc[k][0] = (yac << 16) | xac;
        pc[k][1] = (ybc << 16) | xbc;
    }

    // ---------- Stage addressing (channel-invariant, precomputed) ----------
    int gOff[LD4];   // element offset within a channel plane (row-clamped)
    int lOff[LD4];   // LDS byte offset
    #pragma unroll
    for (int k = 0; k < LD4; ++k) {
        int i = tid + k * NTHREADS;     // 0..1535
        int r = i / 24;                 // region row 0..63
        int j = i - r * 24;             // float4 col 0..23
        int gr = min(max(ys + r, 0), H_ - 1);
        int gx = min(max(xs + 4 * j, 0), W_ - 4);   // stays 16B-aligned
        gOff[k] = gr * W_ + gx;
        lOff[k] = r * (LSTR * 4) + j * 16;
    }

    const float* sp_base = src + (size_t)n * C_ * PLANE;

    float4 pre[LD4];
    #pragma unroll
    for (int k = 0; k < LD4; ++k)
        pre[k] = *(const float4*)(sp_base + gOff[k]);

    // ---------- Channel loop (double-buffered LDS) ----------
    for (int c = 0; c < C_; ++c) {
        int buf = c & 1;
        char* Lw = (char*)&lds[buf][0];
        #pragma unroll
        for (int k = 0; k < LD4; ++k)
            *(float4*)(Lw + lOff[k]) = pre[k];

        float4 nxt[LD4];
        if (c + 1 < C_) {
            const float* sp = sp_base + (size_t)(c + 1) * PLANE;
            #pragma unroll
            for (int k = 0; k < LD4; ++k)
                nxt[k] = *(const float4*)(sp + gOff[k]);
        }

        __syncthreads();   // staged data for channel c visible; also separates
                           // this buffer's prior readers (iter c-2) from its writers

        const char* L = (const char*)&lds[buf][0];
        float* op = out + ((size_t)n * C_ + c) * PLANE;
        const float* sp = sp_base + (size_t)c * PLANE;

        #pragma unroll
        for (int k = 0; k < PXT; ++k) {
            int p = tid + k * NTHREADS;
            int lx = p & (TW - 1);
            int ly = p >> 6;
            float v;
            if (okmask & (1u << k)) {
                int oA = op2[k][0] & 0xffff, oB = ((unsigned)op2[k][0]) >> 16;
                int oC = op2[k][1] & 0xffff, oD = ((unsigned)op2[k][1]) >> 16;
                v = *(const float*)(L + oA) * wt[k][0]
                  + *(const float*)(L + oB) * wt[k][1]
                  + *(const float*)(L + oC) * wt[k][2]
                  + *(const float*)(L + oD) * wt[k][3];
            } else {   // rare |flow|>PAD outlier: exact global gather
                int yac = pc[k][0] >> 16, xac = pc[k][0] & 0xffff;
                int ybc = pc[k][1] >> 16, xbc = pc[k][1] & 0xffff;
                v = sp[yac * W_ + xac] * wt[k][0]
                  + sp[ybc * W_ + xac] * wt[k][1]
                  + sp[yac * W_ + xbc] * wt[k][2]
                  + sp[ybc * W_ + xbc] * wt[k][3];
            }
            op[(size_t)(y0 + ly) * W_ + (x0 + lx)] = v;
        }

        #pragma unroll
        for (int k = 0; k < LD4; ++k) pre[k] = nxt[k];
        // single sync per iteration suffices with double buffering
    }
}

extern "C" void kernel_launch(void* const* d_in, const int* in_sizes, int n_in,
                              void* d_out, int out_size, void* d_ws, size_t ws_size,
                              hipStream_t stream) {
    const float* src  = (const float*)d_in[0];
    const float* flow = (const float*)d_in[1];
    float* out = (float*)d_out;

    int grid = N_ * (H_ / TH) * (W_ / TW);   // 4 * 16 * 8 = 512 blocks
    st_warp_tiled<<<grid, NTHREADS, 0, stream>>>(src, flow, out);
}